// Round 1
// baseline (565.866 us; speedup 1.0000x reference)
//
#include <hip/hip_runtime.h>
#include <hip/hip_bf16.h>

#define B_ 4
#define T_ 128
#define HID 2560
#define NH 8
#define NKV 4
#define HD 256
#define INTER 10240
#define MROWS 512
#define EPS 1e-6f

typedef float f32x4 __attribute__((ext_vector_type(4)));
typedef __bf16 bf16x8 __attribute__((ext_vector_type(8)));
typedef unsigned short us8 __attribute__((ext_vector_type(8)));

__device__ __forceinline__ unsigned short f2bf(float f){
  unsigned int u = __builtin_bit_cast(unsigned int, f);
  u += 0x7fffu + ((u >> 16) & 1u);
  return (unsigned short)(u >> 16);
}

// block-wide sum for 256-thread blocks (4 waves)
__device__ __forceinline__ float bsum256(float v, float* buf){
  #pragma unroll
  for (int o = 32; o; o >>= 1) v += __shfl_xor(v, o);
  __syncthreads();
  if ((threadIdx.x & 63) == 0) buf[threadIdx.x >> 6] = v;
  __syncthreads();
  return buf[0] + buf[1] + buf[2] + buf[3];
}

// ---------------- K1: input RMSNorm -> bf16 ----------------
__global__ __launch_bounds__(256) void rms_in(
    const float* __restrict__ x, const float* __restrict__ w,
    unsigned short* __restrict__ out)
{
  __shared__ float buf[4];
  const int r = blockIdx.x, tid = threadIdx.x;
  const float* xp = x + (size_t)r * HID;
  float v[10]; float ss = 0.f;
  #pragma unroll
  for (int j = 0; j < 10; j++){ v[j] = xp[tid + j*256]; ss += v[j]*v[j]; }
  ss = bsum256(ss, buf);
  float s = rsqrtf(ss * (1.f/HID) + EPS);
  #pragma unroll
  for (int j = 0; j < 10; j++){
    int i = tid + j*256;
    out[(size_t)r*HID + i] = f2bf(v[j] * s * (1.f + w[i]));
  }
}

// ---------------- GEMM: C[split][M][N] = A(bf16,[M][K]) * B(fp32,[N][K])^T ----------------
// 128x128 tile, BK=32, 4 waves (2x2), each wave 64x64 via 4x4 16x16x32 MFMA frags.
__global__ __launch_bounds__(256) void gemm_bf16(
    const unsigned short* __restrict__ A,
    const float* __restrict__ Bw,
    float* __restrict__ C,
    int N, int K, int klen)
{
  __shared__ unsigned short As[128][40];  // +8 pad: stride 80B, 16B-aligned, 2-way banks
  __shared__ unsigned short Bs[128][40];
  const int tid = threadIdx.x;
  const int bm = (blockIdx.x & 3) << 7;       // M=512 fixed -> 4 m-tiles, M-fastest
  const int bn = (blockIdx.x >> 2) << 7;
  const int k0 = blockIdx.y * klen;
  const int k1 = k0 + klen;

  const int srow = tid >> 1;
  const int scol = (tid & 1) << 4;
  const unsigned short* Ap = A + (size_t)(bm + srow) * K + scol;
  const float* Bp = Bw + (size_t)(bn + srow) * K + scol;

  const int wave = tid >> 6;
  const int lane = tid & 63;
  const int wm = (wave & 1) << 6;
  const int wn = (wave >> 1) << 6;
  const int fr = lane & 15;
  const int kq = lane >> 4;

  f32x4 acc[4][4];
  #pragma unroll
  for (int i = 0; i < 4; i++)
    #pragma unroll
    for (int j = 0; j < 4; j++)
      #pragma unroll
      for (int e = 0; e < 4; e++) acc[i][j][e] = 0.f;

  for (int k = k0; k < k1; k += 32) {
    uint4 a0 = *(const uint4*)(Ap + k);
    uint4 a1 = *(const uint4*)(Ap + k + 8);
    float4 b0 = *(const float4*)(Bp + k);
    float4 b1 = *(const float4*)(Bp + k + 4);
    float4 b2 = *(const float4*)(Bp + k + 8);
    float4 b3 = *(const float4*)(Bp + k + 12);
    us8 p0, p1;
    p0[0]=f2bf(b0.x); p0[1]=f2bf(b0.y); p0[2]=f2bf(b0.z); p0[3]=f2bf(b0.w);
    p0[4]=f2bf(b1.x); p0[5]=f2bf(b1.y); p0[6]=f2bf(b1.z); p0[7]=f2bf(b1.w);
    p1[0]=f2bf(b2.x); p1[1]=f2bf(b2.y); p1[2]=f2bf(b2.z); p1[3]=f2bf(b2.w);
    p1[4]=f2bf(b3.x); p1[5]=f2bf(b3.y); p1[6]=f2bf(b3.z); p1[7]=f2bf(b3.w);
    *(uint4*)&As[srow][scol]     = a0;
    *(uint4*)&As[srow][scol + 8] = a1;
    *(us8*)&Bs[srow][scol]       = p0;
    *(us8*)&Bs[srow][scol + 8]   = p1;
    __syncthreads();
    bf16x8 af[4], bfv[4];
    #pragma unroll
    for (int mi = 0; mi < 4; mi++) af[mi]  = *(const bf16x8*)&As[wm + mi*16 + fr][kq*8];
    #pragma unroll
    for (int ni = 0; ni < 4; ni++) bfv[ni] = *(const bf16x8*)&Bs[wn + ni*16 + fr][kq*8];
    #pragma unroll
    for (int mi = 0; mi < 4; mi++)
      #pragma unroll
      for (int ni = 0; ni < 4; ni++)
        acc[mi][ni] = __builtin_amdgcn_mfma_f32_16x16x32_bf16(af[mi], bfv[ni], acc[mi][ni], 0, 0, 0);
    __syncthreads();
  }

  float* Cp = C + (size_t)blockIdx.y * MROWS * N;
  #pragma unroll
  for (int mi = 0; mi < 4; mi++) {
    #pragma unroll
    for (int ni = 0; ni < 4; ni++) {
      int m = bm + wm + mi*16 + kq*4;
      int n = bn + wn + ni*16 + fr;
      #pragma unroll
      for (int i = 0; i < 4; i++)
        Cp[(size_t)(m + i) * N + n] = acc[mi][ni][i];
    }
  }
}

// ---------------- K3: sum qkv splits, QK-norm, RoPE, scatter to q / kT / v ----------------
__global__ __launch_bounds__(64) void qkv_post(
    const float* __restrict__ qkvp,   // [2][512][4096]
    const float* __restrict__ fcos, const float* __restrict__ fsin,  // [128][128]
    const float* __restrict__ qnw, const float* __restrict__ knw,
    float* __restrict__ qout,   // [B][NH][T][256]  (pre-scaled by 1/16)
    float* __restrict__ kT,     // [B][NKV][256][T]
    float* __restrict__ vout)   // [B][NKV][T][256]
{
  const int row = blockIdx.x;        // b*T + t
  const int hh  = blockIdx.y;        // 0..7 q, 8..11 k, 12..15 v
  const int b = row >> 7, t = row & 127;
  const int l = threadIdx.x;
  const float* src  = qkvp + (size_t)row * 4096 + hh * 256;
  const float* src2 = src + (size_t)MROWS * 4096;
  float x[4];
  #pragma unroll
  for (int j = 0; j < 4; j++){ int d = l + j*64; x[j] = src[d] + src2[d]; }

  if (hh >= 12) {
    float* vp = vout + ((size_t)(b*NKV + (hh-12)) * T_ + t) * HD;
    #pragma unroll
    for (int j = 0; j < 4; j++) vp[l + j*64] = x[j];
    return;
  }
  float ss = x[0]*x[0] + x[1]*x[1] + x[2]*x[2] + x[3]*x[3];
  #pragma unroll
  for (int o = 32; o; o >>= 1) ss += __shfl_xor(ss, o);
  float r = rsqrtf(ss * (1.f/HD) + EPS);
  const float* nw = (hh < 8) ? qnw : knw;
  #pragma unroll
  for (int j = 0; j < 4; j++){ int d = l + j*64; x[j] = x[j] * r * (1.f + nw[d]); }
  float c0 = fcos[t*128 + l],      s0 = fsin[t*128 + l];
  float c1 = fcos[t*128 + l + 64], s1 = fsin[t*128 + l + 64];
  float y0 = x[0]*c0 - x[2]*s0;
  float y2 = x[0]*s0 + x[2]*c0;
  float y1 = x[1]*c1 - x[3]*s1;
  float y3 = x[1]*s1 + x[3]*c1;
  if (hh < 8) {
    float* qp = qout + ((size_t)(b*NH + hh) * T_ + t) * HD;
    const float sc = 0.0625f;  // 256^-0.5
    qp[l] = y0*sc; qp[l+64] = y1*sc; qp[l+128] = y2*sc; qp[l+192] = y3*sc;
  } else {
    float* kp = kT + (size_t)(b*NKV + (hh-8)) * HD * T_;
    kp[(size_t)(l)*T_ + t] = y0;  kp[(size_t)(l+64)*T_ + t] = y1;
    kp[(size_t)(l+128)*T_ + t] = y2; kp[(size_t)(l+192)*T_ + t] = y3;
  }
}

// ---------------- K4: causal attention over the 128 written positions ----------------
__global__ __launch_bounds__(128) void attn_fwd(
    const float* __restrict__ q,    // [B][NH][T][256]
    const float* __restrict__ kT,   // [B][NKV][256][T]
    const float* __restrict__ V,    // [B][NKV][T][256]
    unsigned short* __restrict__ attn_out)  // [512][2048] bf16
{
  const int id = blockIdx.x;        // ((b*NH + h)*T + t)
  const int t = id & 127;
  const int h = (id >> 7) & 7;
  const int b = id >> 10;
  const int kvh = h >> 1;
  const int tid = threadIdx.x;
  __shared__ float qs[256];
  __shared__ float sc[128];
  __shared__ float red[128];
  const float* qp = q + (size_t)id * HD;
  qs[tid] = qp[tid]; qs[tid + 128] = qp[tid + 128];
  __syncthreads();
  const float* kp = kT + (size_t)(b*NKV + kvh) * HD * T_;
  float dot = 0.f;
  const bool valid = (tid <= t);
  if (valid) {
    #pragma unroll 8
    for (int d = 0; d < 256; d++) dot += qs[d] * kp[(size_t)d*T_ + tid];
  }
  float score = valid ? 50.f * tanhf(dot * 0.02f) : -3.0e38f;
  sc[tid] = score; red[tid] = score;
  __syncthreads();
  for (int o = 64; o; o >>= 1){ if (tid < o) red[tid] = fmaxf(red[tid], red[tid+o]); __syncthreads(); }
  float m = red[0];
  __syncthreads();
  float p = valid ? __expf(score - m) : 0.f;
  sc[tid] = p; red[tid] = p;
  __syncthreads();
  for (int o = 64; o; o >>= 1){ if (tid < o) red[tid] += red[tid+o]; __syncthreads(); }
  float inv = 1.f / red[0];
  const float* vp = V + (size_t)(b*NKV + kvh) * T_ * HD;
  float a0 = 0.f, a1 = 0.f;
  for (int s = 0; s <= t; s++){
    float ps = sc[s];
    a0 += ps * vp[(size_t)s*HD + tid];
    a1 += ps * vp[(size_t)s*HD + tid + 128];
  }
  size_t orow = ((size_t)(b*T_ + t)) * 2048 + h * 256;
  attn_out[orow + tid]       = f2bf(a0 * inv);
  attn_out[orow + tid + 128] = f2bf(a1 * inv);
}

// ---------------- K6: sum o splits, post-attn norm + residual, pre-ffw norm -> bf16 ----------------
__global__ __launch_bounds__(256) void post_attn_k(
    const float* __restrict__ op, const float* __restrict__ hs,
    const float* __restrict__ wpost, const float* __restrict__ wpre,
    float* __restrict__ h2, unsigned short* __restrict__ xout)
{
  __shared__ float buf[4];
  const int r = blockIdx.x, tid = threadIdx.x;
  const size_t MS = (size_t)MROWS * HID;
  float o[10]; float ss = 0.f;
  #pragma unroll
  for (int j = 0; j < 10; j++){
    size_t i = (size_t)r*HID + tid + j*256;
    float v = op[i] + op[i+MS] + op[i+2*MS] + op[i+3*MS];
    o[j] = v; ss += v*v;
  }
  ss = bsum256(ss, buf);
  float s = rsqrtf(ss*(1.f/HID) + EPS);
  float h[10]; float s2 = 0.f;
  #pragma unroll
  for (int j = 0; j < 10; j++){
    int i = tid + j*256;
    float hv = hs[(size_t)r*HID + i] + o[j]*s*(1.f + wpost[i]);
    h[j] = hv; h2[(size_t)r*HID + i] = hv; s2 += hv*hv;
  }
  s2 = bsum256(s2, buf);
  float sc2 = rsqrtf(s2*(1.f/HID) + EPS);
  #pragma unroll
  for (int j = 0; j < 10; j++){
    int i = tid + j*256;
    xout[(size_t)r*HID + i] = f2bf(h[j]*sc2*(1.f + wpre[i]));
  }
}

// ---------------- K9: act = gelu_tanh(gate) * up -> bf16 ----------------
__global__ __launch_bounds__(256) void act_fuse(
    const float* __restrict__ g, const float* __restrict__ u,
    unsigned short* __restrict__ act, int n)
{
  for (int i = blockIdx.x*256 + threadIdx.x; i < n; i += gridDim.x*256){
    float x = g[i];
    float tt = tanhf(0.7978845608f * (x + 0.044715f * x*x*x));
    float ge = 0.5f * x * (1.f + tt);
    act[i] = f2bf(ge * u[i]);
  }
}

// ---------------- K11: sum down splits, final norm + residual ----------------
__global__ __launch_bounds__(256) void final_k(
    const float* __restrict__ dp, const float* __restrict__ h2,
    const float* __restrict__ w, float* __restrict__ out)
{
  __shared__ float buf[4];
  const int r = blockIdx.x, tid = threadIdx.x;
  const size_t MS = (size_t)MROWS * HID;
  float m[10]; float ss = 0.f;
  #pragma unroll
  for (int j = 0; j < 10; j++){
    size_t i = (size_t)r*HID + tid + j*256;
    float v = dp[i] + dp[i+MS] + dp[i+2*MS] + dp[i+3*MS];
    m[j] = v; ss += v*v;
  }
  ss = bsum256(ss, buf);
  float s = rsqrtf(ss*(1.f/HID) + EPS);
  #pragma unroll
  for (int j = 0; j < 10; j++){
    int i = tid + j*256;
    out[(size_t)r*HID + i] = h2[(size_t)r*HID + i] + m[j]*s*(1.f + w[i]);
  }
}

extern "C" void kernel_launch(void* const* d_in, const int* in_sizes, int n_in,
                              void* d_out, int out_size, void* d_ws, size_t ws_size,
                              hipStream_t stream)
{
  const float* hs     = (const float*)d_in[0];
  const float* fcos   = (const float*)d_in[1];
  const float* fsin   = (const float*)d_in[2];
  const float* w_qkv  = (const float*)d_in[8];
  const float* w_o    = (const float*)d_in[9];
  const float* qnw    = (const float*)d_in[10];
  const float* knw    = (const float*)d_in[11];
  const float* in_ln  = (const float*)d_in[12];
  const float* w_post = (const float*)d_in[13];
  const float* w_pre  = (const float*)d_in[14];
  const float* w_pffw = (const float*)d_in[15];
  const float* w_gate = (const float*)d_in[16];
  const float* w_up   = (const float*)d_in[17];
  const float* w_down = (const float*)d_in[18];
  float* out = (float*)d_out;

  char* p = (char*)d_ws;
  auto alloc = [&](size_t bytes)->void*{ void* r = p; p += (bytes + 255) & ~(size_t)255; return r; };
  unsigned short* h_b   = (unsigned short*)alloc((size_t)MROWS*HID*2);
  float* qkv_p          = (float*)alloc((size_t)2*MROWS*4096*4);
  float* qbuf           = (float*)alloc((size_t)B_*NH*T_*HD*4);
  float* kT             = (float*)alloc((size_t)B_*NKV*HD*T_*4);
  float* vbuf           = (float*)alloc((size_t)B_*NKV*T_*HD*4);
  unsigned short* att_b = (unsigned short*)alloc((size_t)MROWS*2048*2);
  float* o_p            = (float*)alloc((size_t)4*MROWS*HID*4);
  float* h2             = (float*)alloc((size_t)MROWS*HID*4);
  unsigned short* x_b   = (unsigned short*)alloc((size_t)MROWS*HID*2);
  float* gate_p         = (float*)alloc((size_t)MROWS*INTER*4);
  float* up_p           = (float*)alloc((size_t)MROWS*INTER*4);
  unsigned short* act_b = (unsigned short*)alloc((size_t)MROWS*INTER*2);
  float* down_p         = (float*)alloc((size_t)4*MROWS*HID*4);

  rms_in<<<MROWS, 256, 0, stream>>>(hs, in_ln, h_b);
  // qkv: M=512,N=4096,K=2560, splitk=2
  gemm_bf16<<<dim3(4*32, 2), 256, 0, stream>>>(h_b, w_qkv, qkv_p, 4096, 2560, 1280);
  qkv_post<<<dim3(MROWS, 16), 64, 0, stream>>>(qkv_p, fcos, fsin, qnw, knw, qbuf, kT, vbuf);
  attn_fwd<<<B_*NH*T_, 128, 0, stream>>>(qbuf, kT, vbuf, att_b);
  // o: M=512,N=2560,K=2048, splitk=4
  gemm_bf16<<<dim3(4*20, 4), 256, 0, stream>>>(att_b, w_o, o_p, 2560, 2048, 512);
  post_attn_k<<<MROWS, 256, 0, stream>>>(o_p, hs, w_post, w_pre, h2, x_b);
  // gate/up: M=512,N=10240,K=2560, splitk=1
  gemm_bf16<<<dim3(4*80, 1), 256, 0, stream>>>(x_b, w_gate, gate_p, 10240, 2560, 2560);
  gemm_bf16<<<dim3(4*80, 1), 256, 0, stream>>>(x_b, w_up,   up_p,   10240, 2560, 2560);
  act_fuse<<<1024, 256, 0, stream>>>(gate_p, up_p, act_b, MROWS*INTER);
  // down: M=512,N=2560,K=10240, splitk=4
  gemm_bf16<<<dim3(4*20, 4), 256, 0, stream>>>(act_b, w_down, down_p, 2560, 10240, 2560);
  final_k<<<MROWS, 256, 0, stream>>>(down_p, h2, w_pffw, out);
}

// Round 2
// 494.300 us; speedup vs baseline: 1.1448x; 1.1448x over previous
//
#include <hip/hip_runtime.h>
#include <hip/hip_bf16.h>

#define B_ 4
#define T_ 128
#define HID 2560
#define NH 8
#define NKV 4
#define HD 256
#define INTER 10240
#define MROWS 512
#define EPS 1e-6f

typedef float f32x4 __attribute__((ext_vector_type(4)));
typedef __bf16 bf16x8 __attribute__((ext_vector_type(8)));
typedef unsigned short us8 __attribute__((ext_vector_type(8)));

__device__ __forceinline__ unsigned short f2bf(float f){
  unsigned int u = __builtin_bit_cast(unsigned int, f);
  u += 0x7fffu + ((u >> 16) & 1u);
  return (unsigned short)(u >> 16);
}

__device__ __forceinline__ unsigned int cvtpk(float lo, float hi){
  unsigned int r;
  asm("v_cvt_pk_bf16_f32 %0, %1, %2" : "=v"(r) : "v"(lo), "v"(hi));
  return r;
}

// block-wide sum for 256-thread blocks (4 waves)
__device__ __forceinline__ float bsum256(float v, float* buf){
  #pragma unroll
  for (int o = 32; o; o >>= 1) v += __shfl_xor(v, o);
  __syncthreads();
  if ((threadIdx.x & 63) == 0) buf[threadIdx.x >> 6] = v;
  __syncthreads();
  return buf[0] + buf[1] + buf[2] + buf[3];
}

// ---------------- K1: input RMSNorm -> bf16 ----------------
__global__ __launch_bounds__(256) void rms_in(
    const float* __restrict__ x, const float* __restrict__ w,
    unsigned short* __restrict__ out)
{
  __shared__ float buf[4];
  const int r = blockIdx.x, tid = threadIdx.x;
  const float* xp = x + (size_t)r * HID;
  float v[10]; float ss = 0.f;
  #pragma unroll
  for (int j = 0; j < 10; j++){ v[j] = xp[tid + j*256]; ss += v[j]*v[j]; }
  ss = bsum256(ss, buf);
  float s = rsqrtf(ss * (1.f/HID) + EPS);
  #pragma unroll
  for (int j = 0; j < 10; j++){
    int i = tid + j*256;
    out[(size_t)r*HID + i] = f2bf(v[j] * s * (1.f + w[i]));
  }
}

// ---------------- GEMM: C[split][M][N] = A(bf16,[M][K]) * B(fp32,[N][K])^T ----------------
// 128x128 tile, BK=32, 4 waves (2x2), 2-phase prefetch pipeline, dbuf LDS,
// ONE __syncthreads per K-step (placed where vmcnt-in-flight == 0).
__global__ __launch_bounds__(256) void gemm_bf16(
    const unsigned short* __restrict__ A,
    const float* __restrict__ Bw,
    float* __restrict__ C,
    int N, int K, int klen)
{
  __shared__ unsigned short As[2][128][40];  // +8 pad
  __shared__ unsigned short Bs[2][128][40];
  const int tid = threadIdx.x;
  // XCD-chunked swizzle: gridDim.x % 8 == 0 guaranteed by launch config.
  const int bid = (blockIdx.x & 7) * ((int)gridDim.x >> 3) + (blockIdx.x >> 3);
  const int bm = (bid & 3) << 7;       // m fastest within a chunk -> same-B-panel co-XCD
  const int bn = (bid >> 2) << 7;
  const int k0 = blockIdx.y * klen;
  const int nt = klen >> 5;

  const int srow = tid >> 1;
  const int scol = (tid & 1) << 4;
  const unsigned short* Ap = A + (size_t)(bm + srow) * K + k0 + scol;
  const float* Bp = Bw + (size_t)(bn + srow) * K + k0 + scol;

  const int wave = tid >> 6;
  const int lane = tid & 63;
  const int wm = (wave & 1) << 6;
  const int wn = (wave >> 1) << 6;
  const int fr = lane & 15;
  const int kq = lane >> 4;

  f32x4 acc[4][4];
  #pragma unroll
  for (int i = 0; i < 4; i++)
    #pragma unroll
    for (int j = 0; j < 4; j++)
      #pragma unroll
      for (int e = 0; e < 4; e++) acc[i][j][e] = 0.f;

  // prologue: issue loads for tile 0
  uint4  ra0 = *(const uint4*)(Ap);
  uint4  ra1 = *(const uint4*)(Ap + 8);
  float4 rb0 = *(const float4*)(Bp);
  float4 rb1 = *(const float4*)(Bp + 4);
  float4 rb2 = *(const float4*)(Bp + 8);
  float4 rb3 = *(const float4*)(Bp + 12);

  for (int t = 0; t < nt; t++) {
    const int cur = t & 1;
    // ---- stage-write tile t (waits on its loads via compiler vmcnt) ----
    unsigned int q0 = cvtpk(rb0.x, rb0.y), q1 = cvtpk(rb0.z, rb0.w);
    unsigned int q2 = cvtpk(rb1.x, rb1.y), q3 = cvtpk(rb1.z, rb1.w);
    unsigned int q4 = cvtpk(rb2.x, rb2.y), q5 = cvtpk(rb2.z, rb2.w);
    unsigned int q6 = cvtpk(rb3.x, rb3.y), q7 = cvtpk(rb3.z, rb3.w);
    *(uint4*)&As[cur][srow][scol]     = ra0;
    *(uint4*)&As[cur][srow][scol + 8] = ra1;
    uint4 w0; w0.x = q0; w0.y = q1; w0.z = q2; w0.w = q3;
    uint4 w1; w1.x = q4; w1.y = q5; w1.z = q6; w1.w = q7;
    *(uint4*)&Bs[cur][srow][scol]     = w0;
    *(uint4*)&Bs[cur][srow][scol + 8] = w1;
    __syncthreads();   // vmcnt in flight == 0 here -> cheap drain
    // ---- issue loads for tile t+1; overlap with frag reads + MFMA below ----
    if (t + 1 < nt) {
      const unsigned short* Ap2 = Ap + ((t + 1) << 5);
      const float*          Bp2 = Bp + ((t + 1) << 5);
      ra0 = *(const uint4*)(Ap2);
      ra1 = *(const uint4*)(Ap2 + 8);
      rb0 = *(const float4*)(Bp2);
      rb1 = *(const float4*)(Bp2 + 4);
      rb2 = *(const float4*)(Bp2 + 8);
      rb3 = *(const float4*)(Bp2 + 12);
    }
    // ---- compute tile t ----
    bf16x8 af[4], bfv[4];
    #pragma unroll
    for (int mi = 0; mi < 4; mi++) af[mi]  = *(const bf16x8*)&As[cur][wm + mi*16 + fr][kq*8];
    #pragma unroll
    for (int ni = 0; ni < 4; ni++) bfv[ni] = *(const bf16x8*)&Bs[cur][wn + ni*16 + fr][kq*8];
    #pragma unroll
    for (int mi = 0; mi < 4; mi++)
      #pragma unroll
      for (int ni = 0; ni < 4; ni++)
        acc[mi][ni] = __builtin_amdgcn_mfma_f32_16x16x32_bf16(af[mi], bfv[ni], acc[mi][ni], 0, 0, 0);
  }

  float* Cp = C + (size_t)blockIdx.y * MROWS * N;
  #pragma unroll
  for (int mi = 0; mi < 4; mi++) {
    #pragma unroll
    for (int ni = 0; ni < 4; ni++) {
      int m = bm + wm + mi*16 + kq*4;
      int n = bn + wn + ni*16 + fr;
      #pragma unroll
      for (int i = 0; i < 4; i++)
        Cp[(size_t)(m + i) * N + n] = acc[mi][ni][i];
    }
  }
}

// ---------------- K3: sum qkv splits (4), QK-norm, RoPE, scatter to q / kT / v ----------------
__global__ __launch_bounds__(64) void qkv_post(
    const float* __restrict__ qkvp,   // [4][512][4096]
    const float* __restrict__ fcos, const float* __restrict__ fsin,  // [128][128]
    const float* __restrict__ qnw, const float* __restrict__ knw,
    float* __restrict__ qout,   // [B][NH][T][256]  (pre-scaled by 1/16)
    float* __restrict__ kT,     // [B][NKV][256][T]
    float* __restrict__ vout)   // [B][NKV][T][256]
{
  const int row = blockIdx.x;        // b*T + t
  const int hh  = blockIdx.y;        // 0..7 q, 8..11 k, 12..15 v
  const int b = row >> 7, t = row & 127;
  const int l = threadIdx.x;
  const size_t MS = (size_t)MROWS * 4096;
  const float* src = qkvp + (size_t)row * 4096 + hh * 256;
  float x[4];
  #pragma unroll
  for (int j = 0; j < 4; j++){
    int d = l + j*64;
    x[j] = src[d] + src[d + MS] + src[d + 2*MS] + src[d + 3*MS];
  }

  if (hh >= 12) {
    float* vp = vout + ((size_t)(b*NKV + (hh-12)) * T_ + t) * HD;
    #pragma unroll
    for (int j = 0; j < 4; j++) vp[l + j*64] = x[j];
    return;
  }
  float ss = x[0]*x[0] + x[1]*x[1] + x[2]*x[2] + x[3]*x[3];
  #pragma unroll
  for (int o = 32; o; o >>= 1) ss += __shfl_xor(ss, o);
  float r = rsqrtf(ss * (1.f/HD) + EPS);
  const float* nw = (hh < 8) ? qnw : knw;
  #pragma unroll
  for (int j = 0; j < 4; j++){ int d = l + j*64; x[j] = x[j] * r * (1.f + nw[d]); }
  float c0 = fcos[t*128 + l],      s0 = fsin[t*128 + l];
  float c1 = fcos[t*128 + l + 64], s1 = fsin[t*128 + l + 64];
  float y0 = x[0]*c0 - x[2]*s0;
  float y2 = x[0]*s0 + x[2]*c0;
  float y1 = x[1]*c1 - x[3]*s1;
  float y3 = x[1]*s1 + x[3]*c1;
  if (hh < 8) {
    float* qp = qout + ((size_t)(b*NH + hh) * T_ + t) * HD;
    const float sc = 0.0625f;  // 256^-0.5
    qp[l] = y0*sc; qp[l+64] = y1*sc; qp[l+128] = y2*sc; qp[l+192] = y3*sc;
  } else {
    float* kp = kT + (size_t)(b*NKV + (hh-8)) * HD * T_;
    kp[(size_t)(l)*T_ + t] = y0;  kp[(size_t)(l+64)*T_ + t] = y1;
    kp[(size_t)(l+128)*T_ + t] = y2; kp[(size_t)(l+192)*T_ + t] = y3;
  }
}

// ---------------- K4: causal attention over the 128 written positions ----------------
__global__ __launch_bounds__(128) void attn_fwd(
    const float* __restrict__ q,    // [B][NH][T][256]
    const float* __restrict__ kT,   // [B][NKV][256][T]
    const float* __restrict__ V,    // [B][NKV][T][256]
    unsigned short* __restrict__ attn_out)  // [512][2048] bf16
{
  const int id = blockIdx.x;        // ((b*NH + h)*T + t)
  const int t = id & 127;
  const int h = (id >> 7) & 7;
  const int b = id >> 10;
  const int kvh = h >> 1;
  const int tid = threadIdx.x;
  __shared__ float qs[256];
  __shared__ float sc[128];
  __shared__ float red[128];
  const float* qp = q + (size_t)id * HD;
  qs[tid] = qp[tid]; qs[tid + 128] = qp[tid + 128];
  __syncthreads();
  const float* kp = kT + (size_t)(b*NKV + kvh) * HD * T_;
  float dot = 0.f;
  const bool valid = (tid <= t);
  if (valid) {
    #pragma unroll 8
    for (int d = 0; d < 256; d++) dot += qs[d] * kp[(size_t)d*T_ + tid];
  }
  float score = valid ? 50.f * tanhf(dot * 0.02f) : -3.0e38f;
  sc[tid] = score; red[tid] = score;
  __syncthreads();
  for (int o = 64; o; o >>= 1){ if (tid < o) red[tid] = fmaxf(red[tid], red[tid+o]); __syncthreads(); }
  float m = red[0];
  __syncthreads();
  float p = valid ? __expf(score - m) : 0.f;
  sc[tid] = p; red[tid] = p;
  __syncthreads();
  for (int o = 64; o; o >>= 1){ if (tid < o) red[tid] += red[tid+o]; __syncthreads(); }
  float inv = 1.f / red[0];
  const float* vp = V + (size_t)(b*NKV + kvh) * T_ * HD;
  float a0 = 0.f, a1 = 0.f;
  for (int s = 0; s <= t; s++){
    float ps = sc[s];
    a0 += ps * vp[(size_t)s*HD + tid];
    a1 += ps * vp[(size_t)s*HD + tid + 128];
  }
  size_t orow = ((size_t)(b*T_ + t)) * 2048 + h * 256;
  attn_out[orow + tid]       = f2bf(a0 * inv);
  attn_out[orow + tid + 128] = f2bf(a1 * inv);
}

// ---------------- K6: sum o splits (4), post-attn norm + residual, pre-ffw norm -> bf16 ----------------
__global__ __launch_bounds__(256) void post_attn_k(
    const float* __restrict__ op, const float* __restrict__ hs,
    const float* __restrict__ wpost, const float* __restrict__ wpre,
    float* __restrict__ h2, unsigned short* __restrict__ xout)
{
  __shared__ float buf[4];
  const int r = blockIdx.x, tid = threadIdx.x;
  const size_t MS = (size_t)MROWS * HID;
  float o[10]; float ss = 0.f;
  #pragma unroll
  for (int j = 0; j < 10; j++){
    size_t i = (size_t)r*HID + tid + j*256;
    float v = op[i] + op[i+MS] + op[i+2*MS] + op[i+3*MS];
    o[j] = v; ss += v*v;
  }
  ss = bsum256(ss, buf);
  float s = rsqrtf(ss*(1.f/HID) + EPS);
  float h[10]; float s2 = 0.f;
  #pragma unroll
  for (int j = 0; j < 10; j++){
    int i = tid + j*256;
    float hv = hs[(size_t)r*HID + i] + o[j]*s*(1.f + wpost[i]);
    h[j] = hv; h2[(size_t)r*HID + i] = hv; s2 += hv*hv;
  }
  s2 = bsum256(s2, buf);
  float sc2 = rsqrtf(s2*(1.f/HID) + EPS);
  #pragma unroll
  for (int j = 0; j < 10; j++){
    int i = tid + j*256;
    xout[(size_t)r*HID + i] = f2bf(h[j]*sc2*(1.f + wpre[i]));
  }
}

// ---------------- K9: act = gelu_tanh(gate) * up -> bf16 ----------------
__global__ __launch_bounds__(256) void act_fuse(
    const float* __restrict__ g, const float* __restrict__ u,
    unsigned short* __restrict__ act, int n)
{
  for (int i = blockIdx.x*256 + threadIdx.x; i < n; i += gridDim.x*256){
    float x = g[i];
    float tt = tanhf(0.7978845608f * (x + 0.044715f * x*x*x));
    float ge = 0.5f * x * (1.f + tt);
    act[i] = f2bf(ge * u[i]);
  }
}

// ---------------- K11: sum down splits (4), final norm + residual ----------------
__global__ __launch_bounds__(256) void final_k(
    const float* __restrict__ dp, const float* __restrict__ h2,
    const float* __restrict__ w, float* __restrict__ out)
{
  __shared__ float buf[4];
  const int r = blockIdx.x, tid = threadIdx.x;
  const size_t MS = (size_t)MROWS * HID;
  float m[10]; float ss = 0.f;
  #pragma unroll
  for (int j = 0; j < 10; j++){
    size_t i = (size_t)r*HID + tid + j*256;
    float v = dp[i] + dp[i+MS] + dp[i+2*MS] + dp[i+3*MS];
    m[j] = v; ss += v*v;
  }
  ss = bsum256(ss, buf);
  float s = rsqrtf(ss*(1.f/HID) + EPS);
  #pragma unroll
  for (int j = 0; j < 10; j++){
    int i = tid + j*256;
    out[(size_t)r*HID + i] = h2[(size_t)r*HID + i] + m[j]*s*(1.f + w[i]);
  }
}

extern "C" void kernel_launch(void* const* d_in, const int* in_sizes, int n_in,
                              void* d_out, int out_size, void* d_ws, size_t ws_size,
                              hipStream_t stream)
{
  const float* hs     = (const float*)d_in[0];
  const float* fcos   = (const float*)d_in[1];
  const float* fsin   = (const float*)d_in[2];
  const float* w_qkv  = (const float*)d_in[8];
  const float* w_o    = (const float*)d_in[9];
  const float* qnw    = (const float*)d_in[10];
  const float* knw    = (const float*)d_in[11];
  const float* in_ln  = (const float*)d_in[12];
  const float* w_post = (const float*)d_in[13];
  const float* w_pre  = (const float*)d_in[14];
  const float* w_pffw = (const float*)d_in[15];
  const float* w_gate = (const float*)d_in[16];
  const float* w_up   = (const float*)d_in[17];
  const float* w_down = (const float*)d_in[18];
  float* out = (float*)d_out;

  char* p = (char*)d_ws;
  auto alloc = [&](size_t bytes)->void*{ void* r = p; p += (bytes + 255) & ~(size_t)255; return r; };
  unsigned short* h_b   = (unsigned short*)alloc((size_t)MROWS*HID*2);
  float* qkv_p          = (float*)alloc((size_t)4*MROWS*4096*4);
  float* qbuf           = (float*)alloc((size_t)B_*NH*T_*HD*4);
  float* kT             = (float*)alloc((size_t)B_*NKV*HD*T_*4);
  float* vbuf           = (float*)alloc((size_t)B_*NKV*T_*HD*4);
  unsigned short* att_b = (unsigned short*)alloc((size_t)MROWS*2048*2);
  float* o_p            = (float*)alloc((size_t)4*MROWS*HID*4);
  float* h2             = (float*)alloc((size_t)MROWS*HID*4);
  unsigned short* x_b   = (unsigned short*)alloc((size_t)MROWS*HID*2);
  float* gate_p         = (float*)alloc((size_t)MROWS*INTER*4);
  float* up_p           = (float*)alloc((size_t)MROWS*INTER*4);
  unsigned short* act_b = (unsigned short*)alloc((size_t)MROWS*INTER*2);
  float* down_p         = (float*)alloc((size_t)4*MROWS*HID*4);

  rms_in<<<MROWS, 256, 0, stream>>>(hs, in_ln, h_b);
  // qkv: M=512,N=4096,K=2560, splitk=4 (512 blocks)
  gemm_bf16<<<dim3(4*32, 4), 256, 0, stream>>>(h_b, w_qkv, qkv_p, 4096, 2560, 640);
  qkv_post<<<dim3(MROWS, 16), 64, 0, stream>>>(qkv_p, fcos, fsin, qnw, knw, qbuf, kT, vbuf);
  attn_fwd<<<B_*NH*T_, 128, 0, stream>>>(qbuf, kT, vbuf, att_b);
  // o: M=512,N=2560,K=2048, splitk=4 (320 blocks)
  gemm_bf16<<<dim3(4*20, 4), 256, 0, stream>>>(att_b, w_o, o_p, 2560, 2048, 512);
  post_attn_k<<<MROWS, 256, 0, stream>>>(o_p, hs, w_post, w_pre, h2, x_b);
  // gate/up: M=512,N=10240,K=2560, splitk=1 (320 blocks each)
  gemm_bf16<<<dim3(4*80, 1), 256, 0, stream>>>(x_b, w_gate, gate_p, 10240, 2560, 2560);
  gemm_bf16<<<dim3(4*80, 1), 256, 0, stream>>>(x_b, w_up,   up_p,   10240, 2560, 2560);
  act_fuse<<<1024, 256, 0, stream>>>(gate_p, up_p, act_b, MROWS*INTER);
  // down: M=512,N=2560,K=10240, splitk=4 (320 blocks)
  gemm_bf16<<<dim3(4*20, 4), 256, 0, stream>>>(act_b, w_down, down_p, 2560, 10240, 2560);
  final_k<<<MROWS, 256, 0, stream>>>(down_p, h2, w_pffw, out);
}

// Round 3
// 427.117 us; speedup vs baseline: 1.3248x; 1.1573x over previous
//
#include <hip/hip_runtime.h>
#include <hip/hip_bf16.h>

#define B_ 4
#define T_ 128
#define HID 2560
#define NH 8
#define NKV 4
#define HD 256
#define INTER 10240
#define MROWS 512
#define EPS 1e-6f

typedef float f32x4 __attribute__((ext_vector_type(4)));
typedef __bf16 bf16x8 __attribute__((ext_vector_type(8)));

__device__ __forceinline__ unsigned short f2bf(float f){
  unsigned int u = __builtin_bit_cast(unsigned int, f);
  u += 0x7fffu + ((u >> 16) & 1u);
  return (unsigned short)(u >> 16);
}

__device__ __forceinline__ unsigned int cvtpk(float lo, float hi){
  unsigned int r;
  asm("v_cvt_pk_bf16_f32 %0, %1, %2" : "=v"(r) : "v"(lo), "v"(hi));
  return r;
}

__device__ __forceinline__ float bsum256(float v, float* buf){
  #pragma unroll
  for (int o = 32; o; o >>= 1) v += __shfl_xor(v, o);
  __syncthreads();
  if ((threadIdx.x & 63) == 0) buf[threadIdx.x >> 6] = v;
  __syncthreads();
  return buf[0] + buf[1] + buf[2] + buf[3];
}

// ---------------- K1: input RMSNorm -> bf16 ----------------
__global__ __launch_bounds__(256) void rms_in(
    const float* __restrict__ x, const float* __restrict__ w,
    unsigned short* __restrict__ out)
{
  __shared__ float buf[4];
  const int r = blockIdx.x, tid = threadIdx.x;
  const float* xp = x + (size_t)r * HID;
  float v[10]; float ss = 0.f;
  #pragma unroll
  for (int j = 0; j < 10; j++){ v[j] = xp[tid + j*256]; ss += v[j]*v[j]; }
  ss = bsum256(ss, buf);
  float s = rsqrtf(ss * (1.f/HID) + EPS);
  #pragma unroll
  for (int j = 0; j < 10; j++){
    int i = tid + j*256;
    out[(size_t)r*HID + i] = f2bf(v[j] * s * (1.f + w[i]));
  }
}

// ---------------- GEMM: C[split][M][N] = A(bf16,[M][K]) * B(fp32,[N][K])^T ----------------
// 128Mx64N tile, BK=32, 4 waves (2Mx2N), 2-phase prefetch, dbuf LDS (30KB -> 5 blocks/CU).
// High-TLP design: latency hidden by 4-5 resident blocks per CU, not by deep ILP.
__global__ __launch_bounds__(256) void gemm_bf16(
    const unsigned short* __restrict__ A,
    const float* __restrict__ Bw,
    float* __restrict__ C,
    int N, int K, int klen)
{
  __shared__ unsigned short As[2][128][40];  // +8 pad: 2-way banks on b128 reads
  __shared__ unsigned short Bs[2][64][40];
  const int tid = threadIdx.x;
  // XCD-chunked swizzle (gridDim.x % 8 == 0): m-fastest -> same-B-panel blocks co-XCD
  const int bid = (blockIdx.x & 7) * ((int)gridDim.x >> 3) + (blockIdx.x >> 3);
  const int bm = (bid & 3) << 7;
  const int bn = (bid >> 2) << 6;
  const int k0 = blockIdx.y * klen;
  const int nt = klen >> 5;

  const int arow = tid >> 1, acol = (tid & 1) << 4;
  const int brow = tid >> 2, bcol = (tid & 3) << 3;
  const unsigned short* Ap = A + (size_t)(bm + arow) * K + k0 + acol;
  const float* Bp = Bw + (size_t)(bn + brow) * K + k0 + bcol;

  const int wave = tid >> 6, lane = tid & 63;
  const int wm = (wave & 1) << 6;
  const int wn = (wave >> 1) << 5;
  const int fr = lane & 15, kq = lane >> 4;

  f32x4 acc[4][2];
  #pragma unroll
  for (int i = 0; i < 4; i++)
    #pragma unroll
    for (int j = 0; j < 2; j++)
      #pragma unroll
      for (int e = 0; e < 4; e++) acc[i][j][e] = 0.f;

  // prologue: issue loads for tile 0
  uint4  ra0 = *(const uint4*)(Ap);
  uint4  ra1 = *(const uint4*)(Ap + 8);
  float4 rb0 = *(const float4*)(Bp);
  float4 rb1 = *(const float4*)(Bp + 4);

  for (int t = 0; t < nt; t++) {
    const int cur = t & 1;
    unsigned int q0 = cvtpk(rb0.x, rb0.y), q1 = cvtpk(rb0.z, rb0.w);
    unsigned int q2 = cvtpk(rb1.x, rb1.y), q3 = cvtpk(rb1.z, rb1.w);
    *(uint4*)&As[cur][arow][acol]     = ra0;
    *(uint4*)&As[cur][arow][acol + 8] = ra1;
    uint4 w0; w0.x = q0; w0.y = q1; w0.z = q2; w0.w = q3;
    *(uint4*)&Bs[cur][brow][bcol]     = w0;
    __syncthreads();
    if (t + 1 < nt) {
      const unsigned short* Ap2 = Ap + ((t + 1) << 5);
      const float*          Bp2 = Bp + ((t + 1) << 5);
      ra0 = *(const uint4*)(Ap2);
      ra1 = *(const uint4*)(Ap2 + 8);
      rb0 = *(const float4*)(Bp2);
      rb1 = *(const float4*)(Bp2 + 4);
    }
    bf16x8 af[4], bfv[2];
    #pragma unroll
    for (int mi = 0; mi < 4; mi++) af[mi]  = *(const bf16x8*)&As[cur][wm + mi*16 + fr][kq*8];
    #pragma unroll
    for (int ni = 0; ni < 2; ni++) bfv[ni] = *(const bf16x8*)&Bs[cur][wn + ni*16 + fr][kq*8];
    #pragma unroll
    for (int mi = 0; mi < 4; mi++)
      #pragma unroll
      for (int ni = 0; ni < 2; ni++)
        acc[mi][ni] = __builtin_amdgcn_mfma_f32_16x16x32_bf16(af[mi], bfv[ni], acc[mi][ni], 0, 0, 0);
  }

  float* Cp = C + (size_t)blockIdx.y * MROWS * N;
  #pragma unroll
  for (int mi = 0; mi < 4; mi++) {
    #pragma unroll
    for (int ni = 0; ni < 2; ni++) {
      int m = bm + wm + mi*16 + kq*4;
      int n = bn + wn + ni*16 + fr;
      #pragma unroll
      for (int i = 0; i < 4; i++)
        Cp[(size_t)(m + i) * N + n] = acc[mi][ni][i];
    }
  }
}

// ---------------- K3: sum qkv splits (4), QK-norm, RoPE, scatter to q / kT / v ----------------
__global__ __launch_bounds__(64) void qkv_post(
    const float* __restrict__ qkvp,   // [4][512][4096]
    const float* __restrict__ fcos, const float* __restrict__ fsin,
    const float* __restrict__ qnw, const float* __restrict__ knw,
    float* __restrict__ qout, float* __restrict__ kT, float* __restrict__ vout)
{
  const int row = blockIdx.x;
  const int hh  = blockIdx.y;
  const int b = row >> 7, t = row & 127;
  const int l = threadIdx.x;
  const size_t MS = (size_t)MROWS * 4096;
  const float* src = qkvp + (size_t)row * 4096 + hh * 256;
  float x[4];
  #pragma unroll
  for (int j = 0; j < 4; j++){
    int d = l + j*64;
    x[j] = src[d] + src[d + MS] + src[d + 2*MS] + src[d + 3*MS];
  }
  if (hh >= 12) {
    float* vp = vout + ((size_t)(b*NKV + (hh-12)) * T_ + t) * HD;
    #pragma unroll
    for (int j = 0; j < 4; j++) vp[l + j*64] = x[j];
    return;
  }
  float ss = x[0]*x[0] + x[1]*x[1] + x[2]*x[2] + x[3]*x[3];
  #pragma unroll
  for (int o = 32; o; o >>= 1) ss += __shfl_xor(ss, o);
  float r = rsqrtf(ss * (1.f/HD) + EPS);
  const float* nw = (hh < 8) ? qnw : knw;
  #pragma unroll
  for (int j = 0; j < 4; j++){ int d = l + j*64; x[j] = x[j] * r * (1.f + nw[d]); }
  float c0 = fcos[t*128 + l],      s0 = fsin[t*128 + l];
  float c1 = fcos[t*128 + l + 64], s1 = fsin[t*128 + l + 64];
  float y0 = x[0]*c0 - x[2]*s0;
  float y2 = x[0]*s0 + x[2]*c0;
  float y1 = x[1]*c1 - x[3]*s1;
  float y3 = x[1]*s1 + x[3]*c1;
  if (hh < 8) {
    float* qp = qout + ((size_t)(b*NH + hh) * T_ + t) * HD;
    const float sc = 0.0625f;
    qp[l] = y0*sc; qp[l+64] = y1*sc; qp[l+128] = y2*sc; qp[l+192] = y3*sc;
  } else {
    float* kp = kT + (size_t)(b*NKV + (hh-8)) * HD * T_;
    kp[(size_t)(l)*T_ + t] = y0;  kp[(size_t)(l+64)*T_ + t] = y1;
    kp[(size_t)(l+128)*T_ + t] = y2; kp[(size_t)(l+192)*T_ + t] = y3;
  }
}

// ---------------- K4: causal attention over the 128 written positions ----------------
__global__ __launch_bounds__(128) void attn_fwd(
    const float* __restrict__ q, const float* __restrict__ kT,
    const float* __restrict__ V, unsigned short* __restrict__ attn_out)
{
  const int id = blockIdx.x;
  const int t = id & 127;
  const int h = (id >> 7) & 7;
  const int b = id >> 10;
  const int kvh = h >> 1;
  const int tid = threadIdx.x;
  __shared__ float qs[256];
  __shared__ float sc[128];
  __shared__ float red[128];
  const float* qp = q + (size_t)id * HD;
  qs[tid] = qp[tid]; qs[tid + 128] = qp[tid + 128];
  __syncthreads();
  const float* kp = kT + (size_t)(b*NKV + kvh) * HD * T_;
  float dot = 0.f;
  const bool valid = (tid <= t);
  if (valid) {
    #pragma unroll 8
    for (int d = 0; d < 256; d++) dot += qs[d] * kp[(size_t)d*T_ + tid];
  }
  float score = valid ? 50.f * tanhf(dot * 0.02f) : -3.0e38f;
  sc[tid] = score; red[tid] = score;
  __syncthreads();
  for (int o = 64; o; o >>= 1){ if (tid < o) red[tid] = fmaxf(red[tid], red[tid+o]); __syncthreads(); }
  float m = red[0];
  __syncthreads();
  float p = valid ? __expf(score - m) : 0.f;
  sc[tid] = p; red[tid] = p;
  __syncthreads();
  for (int o = 64; o; o >>= 1){ if (tid < o) red[tid] += red[tid+o]; __syncthreads(); }
  float inv = 1.f / red[0];
  const float* vp = V + (size_t)(b*NKV + kvh) * T_ * HD;
  float a0 = 0.f, a1 = 0.f;
  for (int s = 0; s <= t; s++){
    float ps = sc[s];
    a0 += ps * vp[(size_t)s*HD + tid];
    a1 += ps * vp[(size_t)s*HD + tid + 128];
  }
  size_t orow = ((size_t)(b*T_ + t)) * 2048 + h * 256;
  attn_out[orow + tid]       = f2bf(a0 * inv);
  attn_out[orow + tid + 128] = f2bf(a1 * inv);
}

// ---------------- K6: sum o splits (8), post-attn norm + residual, pre-ffw norm -> bf16 ----------------
__global__ __launch_bounds__(256) void post_attn_k(
    const float* __restrict__ op, const float* __restrict__ hs,
    const float* __restrict__ wpost, const float* __restrict__ wpre,
    float* __restrict__ h2, unsigned short* __restrict__ xout)
{
  __shared__ float buf[4];
  const int r = blockIdx.x, tid = threadIdx.x;
  const size_t MS = (size_t)MROWS * HID;
  float o[10]; float ss = 0.f;
  #pragma unroll
  for (int j = 0; j < 10; j++){
    size_t i = (size_t)r*HID + tid + j*256;
    float v = 0.f;
    #pragma unroll
    for (int s = 0; s < 8; s++) v += op[i + s*MS];
    o[j] = v; ss += v*v;
  }
  ss = bsum256(ss, buf);
  float s = rsqrtf(ss*(1.f/HID) + EPS);
  float h[10]; float s2 = 0.f;
  #pragma unroll
  for (int j = 0; j < 10; j++){
    int i = tid + j*256;
    float hv = hs[(size_t)r*HID + i] + o[j]*s*(1.f + wpost[i]);
    h[j] = hv; h2[(size_t)r*HID + i] = hv; s2 += hv*hv;
  }
  s2 = bsum256(s2, buf);
  float sc2 = rsqrtf(s2*(1.f/HID) + EPS);
  #pragma unroll
  for (int j = 0; j < 10; j++){
    int i = tid + j*256;
    xout[(size_t)r*HID + i] = f2bf(h[j]*sc2*(1.f + wpre[i]));
  }
}

// ---------------- K9: act = gelu_tanh(gate0+gate1) * (up0+up1) -> bf16 ----------------
__global__ __launch_bounds__(256) void act_fuse(
    const float* __restrict__ g, const float* __restrict__ u,
    unsigned short* __restrict__ act, int n)
{
  const size_t MS = (size_t)MROWS * INTER;
  for (int i = blockIdx.x*256 + threadIdx.x; i < n; i += gridDim.x*256){
    float x = g[i] + g[i + MS];
    float uu = u[i] + u[i + MS];
    float tt = tanhf(0.7978845608f * (x + 0.044715f * x*x*x));
    float ge = 0.5f * x * (1.f + tt);
    act[i] = f2bf(ge * uu);
  }
}

// ---------------- K11: sum down splits (8), final norm + residual ----------------
__global__ __launch_bounds__(256) void final_k(
    const float* __restrict__ dp, const float* __restrict__ h2,
    const float* __restrict__ w, float* __restrict__ out)
{
  __shared__ float buf[4];
  const int r = blockIdx.x, tid = threadIdx.x;
  const size_t MS = (size_t)MROWS * HID;
  float m[10]; float ss = 0.f;
  #pragma unroll
  for (int j = 0; j < 10; j++){
    size_t i = (size_t)r*HID + tid + j*256;
    float v = 0.f;
    #pragma unroll
    for (int s = 0; s < 8; s++) v += dp[i + s*MS];
    m[j] = v; ss += v*v;
  }
  ss = bsum256(ss, buf);
  float s = rsqrtf(ss*(1.f/HID) + EPS);
  #pragma unroll
  for (int j = 0; j < 10; j++){
    int i = tid + j*256;
    out[(size_t)r*HID + i] = h2[(size_t)r*HID + i] + m[j]*s*(1.f + w[i]);
  }
}

extern "C" void kernel_launch(void* const* d_in, const int* in_sizes, int n_in,
                              void* d_out, int out_size, void* d_ws, size_t ws_size,
                              hipStream_t stream)
{
  const float* hs     = (const float*)d_in[0];
  const float* fcos   = (const float*)d_in[1];
  const float* fsin   = (const float*)d_in[2];
  const float* w_qkv  = (const float*)d_in[8];
  const float* w_o    = (const float*)d_in[9];
  const float* qnw    = (const float*)d_in[10];
  const float* knw    = (const float*)d_in[11];
  const float* in_ln  = (const float*)d_in[12];
  const float* w_post = (const float*)d_in[13];
  const float* w_pre  = (const float*)d_in[14];
  const float* w_pffw = (const float*)d_in[15];
  const float* w_gate = (const float*)d_in[16];
  const float* w_up   = (const float*)d_in[17];
  const float* w_down = (const float*)d_in[18];
  float* out = (float*)d_out;

  char* p = (char*)d_ws;
  auto alloc = [&](size_t bytes)->void*{ void* r = p; p += (bytes + 255) & ~(size_t)255; return r; };
  const size_t SEG = (size_t)2*MROWS*INTER*4;   // 41.9MB
  unsigned short* h_b   = (unsigned short*)alloc((size_t)MROWS*HID*2);
  float* P0             = (float*)alloc(SEG);   // qkv_p (33.5MB) then gate_p (41.9MB)
  float* P1             = (float*)alloc(SEG);   // o_p (41.9MB) then up_p (41.9MB)
  float* P2             = (float*)alloc(SEG);   // down_p (41.9MB)
  float* qbuf           = (float*)alloc((size_t)B_*NH*T_*HD*4);
  float* kT             = (float*)alloc((size_t)B_*NKV*HD*T_*4);
  float* vbuf           = (float*)alloc((size_t)B_*NKV*T_*HD*4);
  unsigned short* att_b = (unsigned short*)alloc((size_t)MROWS*2048*2);
  float* h2             = (float*)alloc((size_t)MROWS*HID*4);
  unsigned short* x_b   = (unsigned short*)alloc((size_t)MROWS*HID*2);
  unsigned short* act_b = (unsigned short*)alloc((size_t)MROWS*INTER*2);

  float* qkv_p  = P0;
  float* gate_p = P0;
  float* o_p    = P1;
  float* up_p   = P1;
  float* down_p = P2;

  rms_in<<<MROWS, 256, 0, stream>>>(hs, in_ln, h_b);
  // qkv: M=512,N=4096,K=2560 -> 256 tiles x 4 splits = 1024 blocks
  gemm_bf16<<<dim3(256, 4), 256, 0, stream>>>(h_b, w_qkv, qkv_p, 4096, 2560, 640);
  qkv_post<<<dim3(MROWS, 16), 64, 0, stream>>>(qkv_p, fcos, fsin, qnw, knw, qbuf, kT, vbuf);
  attn_fwd<<<B_*NH*T_, 128, 0, stream>>>(qbuf, kT, vbuf, att_b);
  // o: M=512,N=2560,K=2048 -> 160 tiles x 8 splits = 1280 blocks
  gemm_bf16<<<dim3(160, 8), 256, 0, stream>>>(att_b, w_o, o_p, 2560, 2048, 256);
  post_attn_k<<<MROWS, 256, 0, stream>>>(o_p, hs, w_post, w_pre, h2, x_b);
  // gate/up: M=512,N=10240,K=2560 -> 640 tiles x 2 splits = 1280 blocks
  gemm_bf16<<<dim3(640, 2), 256, 0, stream>>>(x_b, w_gate, gate_p, 10240, 2560, 1280);
  gemm_bf16<<<dim3(640, 2), 256, 0, stream>>>(x_b, w_up,   up_p,   10240, 2560, 1280);
  act_fuse<<<1024, 256, 0, stream>>>(gate_p, up_p, act_b, MROWS*INTER);
  // down: M=512,N=2560,K=10240 -> 160 tiles x 8 splits = 1280 blocks
  gemm_bf16<<<dim3(160, 8), 256, 0, stream>>>(act_b, w_down, down_p, 2560, 10240, 1280);
  final_k<<<MROWS, 256, 0, stream>>>(down_p, h2, w_pffw, out);
}